// Round 3
// baseline (196.029 us; speedup 1.0000x reference)
//
#include <hip/hip_runtime.h>
#include <cstddef>

// Problem constants (match reference)
constexpr int Bn   = 2048;
constexpr int Dn   = 512;
constexpr int NCLS = 100;
constexpr int CAP  = 131072;      // window key capacity (expect ~41K)
constexpr unsigned WWIN = 32768;  // window width in key units (ulp = 2^-20 at |L|~14.3)

// VERIFIED INVARIANT (R4): reference adc[i][j] = fl32( single fma chain k=0..511 ) / 0.07f,
// strict ascending k, one fused fma per step, single fp32 accumulator. DO NOT reassociate,
// split K, or use MFMA — masks flip at sub-ulp rank gaps.
// adc bitwise symmetric -> lower triangle + mirror. Row max == diag == fl32(chain(F[i]·F[i]))/0.07f.
// STABILITY (R9-R11 bisect): 528-block/256-thread gemm structure is HW-proven; single-wave
// 2080-block variant killed containers twice. Do not revisit.
// R14 LESSON (measured): gemm is LDS-PIPE-bound: LDS:VALU cycle ratio = 6(m+n)/mn per microtile;
// 4x4 => 3.0x (VALUBusy ~30% matches). Smaller microtiles regress despite occupancy gains.
// R15 LESSON (measured): atomic-free finalize + R0 gemm = 173.6us; ~110us is NOT in gemm and
// not visible in top-5 -> dispatch-boundary cost suspected (5 serial dispatches).
// R16: cut dispatches 5->3. select_k merged into gemm via last-block ticket (done==527);
// finalize merged into final_k via ticket (singles==511). Cross-block data read with
// __hip_atomic_load(AGENT) after threadfence-release/ticket-acquire (per-XCD L2 non-coherent;
// writers flush via __threadfence before ticket). Proven R0 pattern, no spinning.
// Mask planes start at out+1 (4-mod-16 addresses): 16B stores only via __builtin_memcpy;
// never cast to float4*.

struct Ctl {
  unsigned above;      // 0:  # negatives with key >= window hi
  unsigned candCount;  // 4:  # keys collected in window
  unsigned singles;    // 8:  final_k ticket (zeroed by rowdot)
  unsigned done;       // 12: gemm ticket (zeroed by rowdot)
  float    thrF;       // 16
  unsigned pad1;       // 20
  double   lossSum;    // 24..31 (unused; layout kept)
  unsigned hist[4096]; // 32; window histogram, 8-ulp bins (built in gemm epilogue)
  unsigned cand[CAP];  // 16416; 16-byte aligned
};
static_assert(offsetof(Ctl, cand) % 16 == 0, "cand must be 16B aligned");
static_assert(offsetof(Ctl, cand) == 16416, "zeroed head size");

// Monotone fp32 <-> uint32 order keys
__device__ inline unsigned key_of(float L) {
  unsigned u = __float_as_uint(L);
  return (u & 0x80000000u) ? ~u : (u | 0x80000000u);
}
__device__ inline float key_to_float(unsigned key) {
  unsigned u = (key & 0x80000000u) ? (key ^ 0x80000000u) : ~key;
  return __uint_as_float(u);
}
// Window: centered at -1/0.07 (negative-pair median), +-16384 ulps (~28 sigma of median est.)
__device__ inline unsigned wlo_key() {
  const float c0 = -1.0f / 0.07f;
  return key_of(c0) - (WWIN / 2);
}
// 16B store to a 4B-aligned address (compiler emits legal dword stores)
__device__ inline void store16_a4(float* p, float4 v) {
  __builtin_memcpy((void*)p, &v, 16);
}
// Agent-scope (device) coherent scalar accessors — bypass per-XCD L2 for cross-block data
__device__ inline unsigned agent_load_u32(const unsigned* p) {
  return __hip_atomic_load(p, __ATOMIC_RELAXED, __HIP_MEMORY_SCOPE_AGENT);
}
__device__ inline double agent_load_f64(const double* p) {
  return __hip_atomic_load(p, __ATOMIC_RELAXED, __HIP_MEMORY_SCOPE_AGENT);
}
__device__ inline void agent_store_f64(double* p, double v) {
  __hip_atomic_store(p, v, __ATOMIC_RELAXED, __HIP_MEMORY_SCOPE_AGENT);
}
__device__ inline void agent_store_u32(unsigned* p, unsigned v) {
  __hip_atomic_store(p, v, __ATOMIC_RELAXED, __HIP_MEMORY_SCOPE_AGENT);
}

// ------- per-row self-dot: rm[i] bitwise == adc[i][i]; fused Ctl zeroing. 32 blocks x 64 -------
__global__ __launch_bounds__(64) void rowdot_k(const float* __restrict__ F,
                                               float* __restrict__ rm, Ctl* c) {
  const int i = blockIdx.x * 64 + threadIdx.x;
  const float4* p = (const float4*)(F + (size_t)i * Dn);
  float acc = 0.0f;
#pragma unroll 16
  for (int q = 0; q < 128; ++q) {
    const float4 f = p[q];
    acc = __builtin_fmaf(f.x, f.x, acc);
    acc = __builtin_fmaf(f.y, f.y, acc);
    acc = __builtin_fmaf(f.z, f.z, acc);
    acc = __builtin_fmaf(f.w, f.w, acc);   // strict ascending-k chain, same as gemm
  }
  rm[i] = acc / 0.07f;                     // IEEE fp32 div: bitwise == adc[i][i]
  // fused Ctl head+hist zeroing; 4104 dwords = 16416 B (covers tickets at offs 8,12)
  unsigned* cz = (unsigned*)c;
  for (int idx = i; idx < 4104; idx += 2048) cz[idx] = 0;
}

// -------- GEMM: lower-triangle 64x64 tiles + mirror + fused window stats (R12-proven) --------
// R16: + last-block (ticket==527) select tail: class-count -> k, hist -> bucket, cand scan,
// exact rank within bucket -> c->thrF. Arithmetic identical to old select_k (bitwise thrF).
__global__ __launch_bounds__(256) void gemm_adc(const float* __restrict__ F,
                                                const float* __restrict__ rm,
                                                const int* __restrict__ labels,
                                                float* __restrict__ adc, Ctl* c) {
  __shared__ float smem[4352];   // As dbuf [0,2176), Bs dbuf [2176,4352); reused: transpose, select
  __shared__ int slabi[64], slabj[64];
  __shared__ float rmiA[64], rmjA[64];
  __shared__ unsigned wlist[1024];
  __shared__ unsigned wcnt, abcnt, gbase;
  __shared__ unsigned amlast;
  __shared__ unsigned skk2, sab2, m2;
  __shared__ int sbd2;
  const int t = threadIdx.x;
  int r = 0;
  { const int idx = blockIdx.x; while ((r + 1) * (r + 2) / 2 <= idx) ++r; }
  const int cc = blockIdx.x - r * (r + 1) / 2;
  const int i0 = r * 64, j0 = cc * 64;

  const int tx = t & 15, ty = t >> 4;        // 16x16 thread grid, 4x4 microtile
  const int lrow = t >> 2, lq = t & 3;       // loader: row 0..63, k-quad 0..3

  if (t < 64) {
    slabi[t] = labels[i0 + t]; rmiA[t] = rm[i0 + t];
    slabj[t] = labels[j0 + t]; rmjA[t] = rm[j0 + t];
  }
  if (t == 0) { wcnt = 0; abcnt = 0; gbase = 0; }

  float acc[4][4] = {};
  const float* Ab = F + (size_t)(i0 + lrow) * Dn;
  const float* Bb = F + (size_t)(j0 + lrow) * Dn;
  float* As = smem;          // [buf*1088 + k*68 + row]
  float* Bs = smem + 2176;

  float4 a = *(const float4*)(Ab + lq * 4);
  float4 b = *(const float4*)(Bb + lq * 4);
  {
    const int k0 = lq * 4;
    As[(k0 + 0) * 68 + lrow] = a.x; As[(k0 + 1) * 68 + lrow] = a.y;
    As[(k0 + 2) * 68 + lrow] = a.z; As[(k0 + 3) * 68 + lrow] = a.w;
    Bs[(k0 + 0) * 68 + lrow] = b.x; Bs[(k0 + 1) * 68 + lrow] = b.y;
    Bs[(k0 + 2) * 68 + lrow] = b.z; Bs[(k0 + 3) * 68 + lrow] = b.w;
  }
  __syncthreads();

  for (int ch = 0; ch < 32; ++ch) {
    const int cur = ch & 1, nxt = cur ^ 1;
    if (ch < 31) {
      const int kg = (ch + 1) * 16;
      a = *(const float4*)(Ab + kg + lq * 4);
      b = *(const float4*)(Bb + kg + lq * 4);
    }
    const float* Ac = As + cur * 1088;
    const float* Bc = Bs + cur * 1088;
#pragma unroll
    for (int k = 0; k < 16; ++k) {
      const float4 av = *(const float4*)(Ac + k * 68 + ty * 4);
      const float4 bv = *(const float4*)(Bc + k * 68 + tx * 4);
      const float aa[4] = {av.x, av.y, av.z, av.w};
      const float bb[4] = {bv.x, bv.y, bv.z, bv.w};
#pragma unroll
      for (int m = 0; m < 4; ++m)
#pragma unroll
        for (int n = 0; n < 4; ++n)
          acc[m][n] = __builtin_fmaf(aa[m], bb[n], acc[m][n]);  // strict k-order chain
    }
    if (ch < 31) {
      const int k0 = lq * 4;
      float* An = As + nxt * 1088;
      float* Bm = Bs + nxt * 1088;
      An[(k0 + 0) * 68 + lrow] = a.x; An[(k0 + 1) * 68 + lrow] = a.y;
      An[(k0 + 2) * 68 + lrow] = a.z; An[(k0 + 3) * 68 + lrow] = a.w;
      Bm[(k0 + 0) * 68 + lrow] = b.x; Bm[(k0 + 1) * 68 + lrow] = b.y;
      Bm[(k0 + 2) * 68 + lrow] = b.z; Bm[(k0 + 3) * 68 + lrow] = b.w;
    }
    __syncthreads();
  }

  // epilogue: /0.07f, store own tile
  float v[4][4];
#pragma unroll
  for (int m = 0; m < 4; ++m) {
#pragma unroll
    for (int n = 0; n < 4; ++n) v[m][n] = acc[m][n] / 0.07f;   // IEEE fp32 div
    float4 q = {v[m][0], v[m][1], v[m][2], v[m][3]};
    *(float4*)&adc[(size_t)(i0 + ty * 4 + m) * Bn + j0 + tx * 4] = q;
  }
  if (r != cc) {
    // mirror via LDS transpose (bitwise-identical values)
    __syncthreads();               // block-uniform; k-loop LDS reads done
    float* T = smem;               // 64 x 68
#pragma unroll
    for (int m = 0; m < 4; ++m)
#pragma unroll
      for (int n = 0; n < 4; ++n)
        T[(tx * 4 + n) * 68 + (ty * 4 + m)] = v[m][n];
    __syncthreads();
#pragma unroll
    for (int e = 0; e < 4; ++e) {
      const int row2 = e * 16 + ty;  // mirror row = original col
      *(float4*)&adc[(size_t)(j0 + row2) * Bn + i0 + tx * 4] =
          *(const float4*)(T + row2 * 68 + tx * 4);
    }
  }

  // fused window statistics (own tile + mirror), values still in registers
  __syncthreads();
  const unsigned klo = wlo_key(), khi = klo + WWIN;
  unsigned myab = 0;
#pragma unroll
  for (int m = 0; m < 4; ++m) {
    const int gi = i0 + ty * 4 + m;
    const int li = slabi[ty * 4 + m];
    const float rmi = rmiA[ty * 4 + m];
#pragma unroll
    for (int n = 0; n < 4; ++n) {
      const int gj = j0 + tx * 4 + n;
      if (gi == gj || li == slabj[tx * 4 + n]) continue;
      const unsigned key = key_of(v[m][n] - rmi);   // exact fp32 sub
      if (key >= khi) ++myab;
      else if (key >= klo) {
        atomicAdd(&c->hist[(key - klo) >> 3], 1u);
        const unsigned p = atomicAdd(&wcnt, 1u);
        if (p < 1024u) wlist[p] = key;
      }
      if (r != cc) {
        const unsigned key2 = key_of(v[m][n] - rmjA[tx * 4 + n]);
        if (key2 >= khi) ++myab;
        else if (key2 >= klo) {
          atomicAdd(&c->hist[(key2 - klo) >> 3], 1u);
          const unsigned p = atomicAdd(&wcnt, 1u);
          if (p < 1024u) wlist[p] = key2;
        }
      }
    }
  }
  if (myab) atomicAdd(&abcnt, myab);
  __syncthreads();
  if (t == 0) {
    if (abcnt) atomicAdd(&c->above, abcnt);
    const unsigned nl = wcnt < 1024u ? wcnt : 1024u;
    gbase = nl ? atomicAdd(&c->candCount, nl) : 0u;
  }
  __syncthreads();
  const unsigned nl = wcnt < 1024u ? wcnt : 1024u;
  for (unsigned q = t; q < nl; q += 256) {
    const unsigned p = gbase + q;
    if (p < (unsigned)CAP) c->cand[p] = wlist[q];
  }

  // ---------------- last-block select tail (ticket == 527) ----------------
  __syncthreads();                 // all this block's cand stores issued & drained
  if (t == 0) {
    __threadfence();               // release: write back dirty L2 lines (cand) device-wide
    amlast = (atomicAdd(&c->done, 1u) == 527u) ? 1u : 0u;
  }
  __syncthreads();
  if (!amlast) return;
  __threadfence();                 // acquire side

  // LDS overlay (k-loop/transpose storage is dead here)
  unsigned* s_cnt    = (unsigned*)smem;        // [0,128)
  unsigned* s_tsum   = (unsigned*)smem + 128;  // [128,384)
  unsigned* s_suffix = (unsigned*)smem + 384;  // [384,640)
  unsigned* s_list   = (unsigned*)smem + 640;  // [640,896)
  if (t < NCLS) s_cnt[t] = 0;
  if (t == 0) { m2 = 0; sbd2 = 0; sab2 = 0; }
  __syncthreads();
  for (int j = t; j < Bn; j += 256) atomicAdd(&s_cnt[labels[j]], 1u);
  __syncthreads();
  if (t == 0) {
    unsigned s2 = 0;
    for (int hh = 0; hh < NCLS; ++hh) s2 += s_cnt[hh] * s_cnt[hh];
    unsigned nneg = (unsigned)Bn * Bn - s2;
    unsigned k = nneg >> 1;                  // floor(0.5*n_neg), exact vs ref
    if (k < 1) k = 1;
    skk2 = k;
  }
  unsigned hv[16];
  unsigned ssum = 0;
#pragma unroll
  for (int u = 0; u < 16; ++u) {
    hv[u] = agent_load_u32(&c->hist[t * 16 + u]);
    ssum += hv[u];
  }
  s_tsum[t] = ssum;
  __syncthreads();
  if (t == 0) {
    unsigned accu = agent_load_u32(&c->above);
    for (int q2 = 255; q2 >= 0; --q2) { s_suffix[q2] = accu; accu += s_tsum[q2]; }
  }
  __syncthreads();
  const unsigned kk = skk2;
  unsigned cum = s_suffix[t];
#pragma unroll
  for (int u = 15; u >= 0; --u) {
    if (cum < kk && cum + hv[u] >= kk) { sbd2 = t * 16 + u; sab2 = cum; }
    cum += hv[u];
  }
  __syncthreads();
  const int bd = sbd2;
  const unsigned rrk = kk - sab2;  // 1-indexed rank within bucket
  unsigned n = agent_load_u32(&c->candCount);
  if (n > (unsigned)CAP) n = (unsigned)CAP;
  unsigned e = t;
  for (; e + 7u * 256u < n; e += 8u * 256u) {   // 8 independent agent loads in flight
    unsigned ks[8];
#pragma unroll
    for (int u = 0; u < 8; ++u) ks[u] = agent_load_u32(&c->cand[e + (unsigned)u * 256u]);
#pragma unroll
    for (int u = 0; u < 8; ++u) {
      const unsigned d = ks[u] - klo;
      if (d < WWIN && (int)(d >> 3) == bd) {
        const unsigned p = atomicAdd(&m2, 1u);
        if (p < 256u) s_list[p] = ks[u];
      }
    }
  }
  for (; e < n; e += 256u) {
    const unsigned kv = agent_load_u32(&c->cand[e]);
    const unsigned d = kv - klo;
    if (d < WWIN && (int)(d >> 3) == bd) {
      const unsigned p = atomicAdd(&m2, 1u);
      if (p < 256u) s_list[p] = kv;
    }
  }
  __syncthreads();
  const unsigned mm = m2 > 256u ? 256u : m2;
  for (unsigned e2 = t; e2 < mm; e2 += 256) {
    const unsigned vv2 = s_list[e2];
    unsigned g = 0, ge = 0;
    for (unsigned j2 = 0; j2 < mm; ++j2) {
      g  += (s_list[j2] > vv2);
      ge += (s_list[j2] >= vv2);
    }
    if (g < rrk && rrk <= ge) c->thrF = key_to_float(vv2);  // duplicates write same value
  }
}

// ------- fused mask + loss: 512 blocks x 4 rows, one wave per row, NO contended atomics -------
// Per-block partials via agent-scope stores; last block (ticket singles==511) reduces & writes out[0].
__global__ __launch_bounds__(256) void final_k(const float* __restrict__ adc,
                                               const int* __restrict__ labels,
                                               Ctl* c,
                                               float* __restrict__ out,
                                               double* __restrict__ lsum_g,
                                               unsigned* __restrict__ scnt_g) {
  __shared__ int slab[Bn];
  __shared__ double lsum[4];
  __shared__ unsigned sflag[4];
  __shared__ unsigned amlast;
  const int t = threadIdx.x;
  const int lane = t & 63, w = t >> 6;
#pragma unroll
  for (int e = 0; e < 2; ++e)                      // int4 slab staging, once per 4 rows
    ((int4*)slab)[t + 256 * e] = ((const int4*)labels)[t + 256 * e];
  __syncthreads();
  const float thr = c->thrF;
  float* __restrict__ ohnm = out + 1;
  float* __restrict__ ofin = out + 1 + (size_t)Bn * Bn;

  const int i = blockIdx.x * 4 + w;                // wave w owns one row
  const int li = slab[i];
  const float rm = adc[(size_t)i * Bn + i];        // diag == row max (bitwise)
  const float4* rowp = (const float4*)(adc + (size_t)i * Bn);
  float se = 0.0f, sp = 0.0f;
  int pc = 0;
#pragma unroll
  for (int q = 0; q < 8; ++q) {
    const int j4 = lane + 64 * q;                  // wave instr covers 1KB contiguous
    const float4 vv = rowp[j4];
    const int jb = j4 * 4;
    const float vs[4] = {vv.x, vv.y, vv.z, vv.w};
    float qh[4], qf[4];
#pragma unroll
    for (int u = 0; u < 4; ++u) {
      const int j = jb + u;
      const float L = vs[u] - rm;                  // identical fp32 value as gemm epilogue
      const bool offd = (j != i);
      const bool same = (slab[j] == li);
      const bool hnm  = offd && !same && (L >= thr);
      const bool fin  = offd && (same || hnm);
      if (offd) se += __expf(L);
      if (fin)  { sp += L; ++pc; }
      qh[u] = hnm ? 1.0f : 0.0f;
      qf[u] = fin ? 1.0f : 0.0f;
    }
    float4 h4 = {qh[0], qh[1], qh[2], qh[3]};
    float4 f4 = {qf[0], qf[1], qf[2], qf[3]};
    store16_a4(&ohnm[(size_t)i * Bn + jb], h4);    // 4-mod-16 address: memcpy path
    store16_a4(&ofin[(size_t)i * Bn + jb], f4);
  }
  float pcf = (float)pc;
#pragma unroll
  for (int o = 32; o > 0; o >>= 1) {               // wave-only reduction, no barriers
    se  += __shfl_down(se,  o, 64);
    sp  += __shfl_down(sp,  o, 64);
    pcf += __shfl_down(pcf, o, 64);
  }
  if (lane == 0) {
    const double P = (double)pcf;
    const bool single = (P == 0.0);
    const double mlpp = ((double)sp - P * log((double)se + 1e-12)) / (P + (single ? 1.0 : 0.0));
    lsum[w]  = single ? 0.0 : -mlpp;
    sflag[w] = single ? 1u : 0u;
  }
  __syncthreads();
  if (t == 0) {
    agent_store_f64(&lsum_g[blockIdx.x], lsum[0] + lsum[1] + lsum[2] + lsum[3]);
    agent_store_u32(&scnt_g[blockIdx.x], sflag[0] + sflag[1] + sflag[2] + sflag[3]);
    __threadfence();                               // release (mask stores also drained by L2 wb)
    amlast = (atomicAdd(&c->singles, 1u) == 511u) ? 1u : 0u;
  }
  __syncthreads();
  if (!amlast) return;
  __threadfence();                                 // acquire side

  // ---- finalize tail: reduce 512 partials (agent loads bypass stale per-XCD L2) ----
  double ls = agent_load_f64(&lsum_g[t]) + agent_load_f64(&lsum_g[t + 256]);
  unsigned sc = agent_load_u32(&scnt_g[t]) + agent_load_u32(&scnt_g[t + 256]);
#pragma unroll
  for (int o = 32; o > 0; o >>= 1) {
    ls += __shfl_down(ls, o, 64);
    sc += __shfl_down(sc, o, 64);
  }
  if (lane == 0) { lsum[w] = ls; sflag[w] = sc; }  // reuse shared arrays
  __syncthreads();
  if (t == 0) {
    const double tot = lsum[0] + lsum[1] + lsum[2] + lsum[3];
    const unsigned sg = sflag[0] + sflag[1] + sflag[2] + sflag[3];
    out[0] = (float)(tot / ((double)Bn - (double)sg));
  }
}

// ---------------- launch: 3 dispatches ----------------
extern "C" void kernel_launch(void* const* d_in, const int* in_sizes, int n_in,
                              void* d_out, int out_size, void* d_ws, size_t ws_size,
                              hipStream_t stream) {
  const float* F      = (const float*)d_in[0];
  const int*   labels = (const int*)d_in[1];
  float* out = (float*)d_out;

  char* ws = (char*)d_ws;
  Ctl*      c      = (Ctl*)ws;                              // ~541 KB
  float*    rm     = (float*)(ws + 786432);                 // 768 KB offset, 8 KB
  double*   lsum_g = (double*)(ws + 802816);                // 512 doubles, 4 KB
  unsigned* scnt_g = (unsigned*)(ws + 806912);              // 512 uints, 2 KB
  float*    adc    = (float*)(ws + (1u << 20));             // 1 MiB offset, 16.78 MB

  rowdot_k<<<32, 64, 0, stream>>>(F, rm, c);                // self-dots + Ctl zeroing
  gemm_adc<<<528, 256, 0, stream>>>(F, rm, labels, adc, c); // triangle tiles + select tail
  final_k<<<512, 256, 0, stream>>>(adc, labels, c, out, lsum_g, scnt_g); // masks+loss+finalize
}

// Round 4
// 155.604 us; speedup vs baseline: 1.2598x; 1.2598x over previous
//
#include <hip/hip_runtime.h>
#include <cstddef>

// Problem constants (match reference)
constexpr int Bn   = 2048;
constexpr int Dn   = 512;
constexpr int NCLS = 100;
constexpr unsigned WWIN = 32768;  // window width in key units (ulp = 2^-20 at |L|~14.3)
constexpr int NH = 32768;         // 1-ulp histogram bins across the window (R17)

// VERIFIED INVARIANT (R4): reference adc[i][j] = fl32( single fma chain k=0..511 ) / 0.07f,
// strict ascending k, one fused fma per step, single fp32 accumulator. DO NOT reassociate,
// split K, or use MFMA — masks flip at sub-ulp rank gaps.
// adc bitwise symmetric -> lower triangle + mirror. Row max == diag == fl32(chain(F[i]·F[i]))/0.07f.
// STABILITY (R9-R11 bisect): 528-block/256-thread gemm structure is HW-proven; single-wave
// 2080-block variant killed containers twice. Do not revisit.
// R14 LESSON (measured): gemm is LDS-PIPE-bound: LDS:VALU ratio = 6(m+n)/mn per microtile.
// R16 LESSON (measured): agent-scope (__hip_atomic_load) scalar loads serialize at ~700cyc each
// (per-load vmcnt(0)); a 41K-element single-block scan = ~42us idle-machine tail. Fix: 1-ulp
// hist (threshold key == bin key, no cand/rank scan) + PLAIN vector loads in the tail.
// Plain-load coherence argument: hist/above are written ONLY by device-scope atomics (performed
// at the coherent point, never filled into local L2); tail's first plain touch in this dispatch
// misses to the coherent point. Stale lines from rowdot's zeroing are invalidated by the
// dispatch-boundary acquire (same mechanism as R15's proven cross-kernel plain-load finalize).
// R17: no __threadfence anywhere (each was a full L2 writeback, 528+512 of them). gemm ticket
// needs no fence: __syncthreads drains vmcnt (atomics performed) before t0's ticket RMW.
// final_k: t0-only "s_waitcnt vmcnt(0)" between sc-stores and ticket replaces the fence.
// Mask planes start at out+1 (4-mod-16 addresses): 16B stores only via __builtin_memcpy;
// never cast to float4*.

struct Ctl {
  unsigned above;      // 0:  # negatives with key >= window hi (device atomics only)
  unsigned candCount;  // 4:  unused since R17 (layout kept)
  unsigned singles;    // 8:  final_k ticket (zeroed by rowdot)
  unsigned done;       // 12: gemm ticket (zeroed by rowdot)
  float    thrF;       // 16
  unsigned pad1;       // 20
  double   lossSum;    // 24..31 (unused; layout kept)
  unsigned hist[NH];   // 32: 1-ulp bins over window (device atomics only)
};
static_assert(offsetof(Ctl, hist) == 32, "zero loop covers head + hist");

// Monotone fp32 <-> uint32 order keys
__device__ inline unsigned key_of(float L) {
  unsigned u = __float_as_uint(L);
  return (u & 0x80000000u) ? ~u : (u | 0x80000000u);
}
__device__ inline float key_to_float(unsigned key) {
  unsigned u = (key & 0x80000000u) ? (key ^ 0x80000000u) : ~key;
  return __uint_as_float(u);
}
// Window: centered at -1/0.07 (negative-pair median), +-16384 ulps (~28 sigma of median est.)
__device__ inline unsigned wlo_key() {
  const float c0 = -1.0f / 0.07f;
  return key_of(c0) - (WWIN / 2);
}
// 16B store to a 4B-aligned address (compiler emits legal dword stores)
__device__ inline void store16_a4(float* p, float4 v) {
  __builtin_memcpy((void*)p, &v, 16);
}
// Agent-scope write-through stores (to coherent point; reader uses plain first-touch loads)
__device__ inline void agent_store_f64(double* p, double v) {
  __hip_atomic_store(p, v, __ATOMIC_RELAXED, __HIP_MEMORY_SCOPE_AGENT);
}
__device__ inline void agent_store_u32(unsigned* p, unsigned v) {
  __hip_atomic_store(p, v, __ATOMIC_RELAXED, __HIP_MEMORY_SCOPE_AGENT);
}

// ------- per-row self-dot: rm[i] bitwise == adc[i][i]; fused Ctl zeroing. 32 blocks x 64 -------
__global__ __launch_bounds__(64) void rowdot_k(const float* __restrict__ F,
                                               float* __restrict__ rm, Ctl* c) {
  const int i = blockIdx.x * 64 + threadIdx.x;
  const float4* p = (const float4*)(F + (size_t)i * Dn);
  float acc = 0.0f;
#pragma unroll 16
  for (int q = 0; q < 128; ++q) {
    const float4 f = p[q];
    acc = __builtin_fmaf(f.x, f.x, acc);
    acc = __builtin_fmaf(f.y, f.y, acc);
    acc = __builtin_fmaf(f.z, f.z, acc);
    acc = __builtin_fmaf(f.w, f.w, acc);   // strict ascending-k chain, same as gemm
  }
  rm[i] = acc / 0.07f;                     // IEEE fp32 div: bitwise == adc[i][i]
  // fused Ctl head+hist zeroing; 8 + NH = 32776 dwords (covers tickets at offs 8,12)
  unsigned* cz = (unsigned*)c;
  for (int idx = i; idx < 8 + NH; idx += 2048) cz[idx] = 0;
}

// -------- GEMM: lower-triangle 64x64 tiles + mirror + fused 1-ulp window hist --------
// + last-block (ticket==527) select tail: class-count -> k, hist suffix -> exact bin -> thrF.
// Rank semantics identical to old select (1-ulp bin => all keys in bin identical => bin IS the
// k-th key; duplicates counted individually by the suffix sums). Bitwise-identical thrF.
__global__ __launch_bounds__(256) void gemm_adc(const float* __restrict__ F,
                                                const float* __restrict__ rm,
                                                const int* __restrict__ labels,
                                                float* __restrict__ adc, Ctl* c) {
  __shared__ float smem[4352];   // As dbuf [0,2176), Bs dbuf [2176,4352); reused: transpose, tail
  __shared__ int slabi[64], slabj[64];
  __shared__ float rmiA[64], rmjA[64];
  __shared__ unsigned abcnt;
  __shared__ unsigned amlast, skk2;
  const int t = threadIdx.x;
  int r = 0;
  { const int idx = blockIdx.x; while ((r + 1) * (r + 2) / 2 <= idx) ++r; }
  const int cc = blockIdx.x - r * (r + 1) / 2;
  const int i0 = r * 64, j0 = cc * 64;

  const int tx = t & 15, ty = t >> 4;        // 16x16 thread grid, 4x4 microtile
  const int lrow = t >> 2, lq = t & 3;       // loader: row 0..63, k-quad 0..3

  if (t < 64) {
    slabi[t] = labels[i0 + t]; rmiA[t] = rm[i0 + t];
    slabj[t] = labels[j0 + t]; rmjA[t] = rm[j0 + t];
  }
  if (t == 0) abcnt = 0;

  float acc[4][4] = {};
  const float* Ab = F + (size_t)(i0 + lrow) * Dn;
  const float* Bb = F + (size_t)(j0 + lrow) * Dn;
  float* As = smem;          // [buf*1088 + k*68 + row]
  float* Bs = smem + 2176;

  float4 a = *(const float4*)(Ab + lq * 4);
  float4 b = *(const float4*)(Bb + lq * 4);
  {
    const int k0 = lq * 4;
    As[(k0 + 0) * 68 + lrow] = a.x; As[(k0 + 1) * 68 + lrow] = a.y;
    As[(k0 + 2) * 68 + lrow] = a.z; As[(k0 + 3) * 68 + lrow] = a.w;
    Bs[(k0 + 0) * 68 + lrow] = b.x; Bs[(k0 + 1) * 68 + lrow] = b.y;
    Bs[(k0 + 2) * 68 + lrow] = b.z; Bs[(k0 + 3) * 68 + lrow] = b.w;
  }
  __syncthreads();

  for (int ch = 0; ch < 32; ++ch) {
    const int cur = ch & 1, nxt = cur ^ 1;
    if (ch < 31) {
      const int kg = (ch + 1) * 16;
      a = *(const float4*)(Ab + kg + lq * 4);
      b = *(const float4*)(Bb + kg + lq * 4);
    }
    const float* Ac = As + cur * 1088;
    const float* Bc = Bs + cur * 1088;
#pragma unroll
    for (int k = 0; k < 16; ++k) {
      const float4 av = *(const float4*)(Ac + k * 68 + ty * 4);
      const float4 bv = *(const float4*)(Bc + k * 68 + tx * 4);
      const float aa[4] = {av.x, av.y, av.z, av.w};
      const float bb[4] = {bv.x, bv.y, bv.z, bv.w};
#pragma unroll
      for (int m = 0; m < 4; ++m)
#pragma unroll
        for (int n = 0; n < 4; ++n)
          acc[m][n] = __builtin_fmaf(aa[m], bb[n], acc[m][n]);  // strict k-order chain
    }
    if (ch < 31) {
      const int k0 = lq * 4;
      float* An = As + nxt * 1088;
      float* Bm = Bs + nxt * 1088;
      An[(k0 + 0) * 68 + lrow] = a.x; An[(k0 + 1) * 68 + lrow] = a.y;
      An[(k0 + 2) * 68 + lrow] = a.z; An[(k0 + 3) * 68 + lrow] = a.w;
      Bm[(k0 + 0) * 68 + lrow] = b.x; Bm[(k0 + 1) * 68 + lrow] = b.y;
      Bm[(k0 + 2) * 68 + lrow] = b.z; Bm[(k0 + 3) * 68 + lrow] = b.w;
    }
    __syncthreads();
  }

  // epilogue: /0.07f, store own tile
  float v[4][4];
#pragma unroll
  for (int m = 0; m < 4; ++m) {
#pragma unroll
    for (int n = 0; n < 4; ++n) v[m][n] = acc[m][n] / 0.07f;   // IEEE fp32 div
    float4 q = {v[m][0], v[m][1], v[m][2], v[m][3]};
    *(float4*)&adc[(size_t)(i0 + ty * 4 + m) * Bn + j0 + tx * 4] = q;
  }
  if (r != cc) {
    // mirror via LDS transpose (bitwise-identical values)
    __syncthreads();               // block-uniform; k-loop LDS reads done
    float* T = smem;               // 64 x 68
#pragma unroll
    for (int m = 0; m < 4; ++m)
#pragma unroll
      for (int n = 0; n < 4; ++n)
        T[(tx * 4 + n) * 68 + (ty * 4 + m)] = v[m][n];
    __syncthreads();
#pragma unroll
    for (int e = 0; e < 4; ++e) {
      const int row2 = e * 16 + ty;  // mirror row = original col
      *(float4*)&adc[(size_t)(j0 + row2) * Bn + i0 + tx * 4] =
          *(const float4*)(T + row2 * 68 + tx * 4);
    }
  }

  // fused 1-ulp window histogram (own tile + mirror), values still in registers
  __syncthreads();
  const unsigned klo = wlo_key(), khi = klo + WWIN;
  unsigned myab = 0;
#pragma unroll
  for (int m = 0; m < 4; ++m) {
    const int gi = i0 + ty * 4 + m;
    const int li = slabi[ty * 4 + m];
    const float rmi = rmiA[ty * 4 + m];
#pragma unroll
    for (int n = 0; n < 4; ++n) {
      const int gj = j0 + tx * 4 + n;
      if (gi == gj || li == slabj[tx * 4 + n]) continue;
      const unsigned key = key_of(v[m][n] - rmi);   // exact fp32 sub
      if (key >= khi) ++myab;
      else if (key >= klo) atomicAdd(&c->hist[key - klo], 1u);
      if (r != cc) {
        const unsigned key2 = key_of(v[m][n] - rmjA[tx * 4 + n]);
        if (key2 >= khi) ++myab;
        else if (key2 >= klo) atomicAdd(&c->hist[key2 - klo], 1u);
      }
    }
  }
  if (myab) atomicAdd(&abcnt, myab);
  __syncthreads();
  if (t == 0 && abcnt) atomicAdd(&c->above, abcnt);

  // ---------------- last-block select tail (ticket == 527) ----------------
  __syncthreads();                 // barrier waitcnt drains this block's hist/above atomics
  if (t == 0) amlast = (atomicAdd(&c->done, 1u) == 527u) ? 1u : 0u;
  __syncthreads();
  if (!amlast) return;

  // LDS overlay (k-loop/transpose storage is dead here)
  unsigned* s_cnt  = (unsigned*)smem;          // [0,128)
  unsigned* s_tsum = (unsigned*)smem + 128;    // [128,384)
  unsigned* s_sufx = (unsigned*)smem + 384;    // [384,640)
  if (t < NCLS) s_cnt[t] = 0;
  __syncthreads();
  for (int j = t; j < Bn; j += 256) atomicAdd(&s_cnt[labels[j]], 1u);
  __syncthreads();
  if (t == 0) {
    unsigned s2 = 0;
    for (int hh = 0; hh < NCLS; ++hh) s2 += s_cnt[hh] * s_cnt[hh];
    unsigned nneg = (unsigned)Bn * Bn - s2;
    unsigned k = nneg >> 1;                  // floor(0.5*n_neg), exact vs ref
    if (k < 1) k = 1;
    skk2 = k;
  }
  // pass 1: per-thread bin sums (plain vector loads; first touch -> coherent point)
  const uint4* hp = (const uint4*)c->hist;   // 8192 quads; thread t owns quads [t*32, t*32+32)
  unsigned s = 0;
#pragma unroll 8
  for (int bq = 0; bq < 32; ++bq) {
    const uint4 vq = hp[t * 32 + bq];
    s += vq.x + vq.y + vq.z + vq.w;
  }
  s_tsum[t] = s;
  __syncthreads();
  if (t == 0) {
    unsigned accu = c->above;                // atomic-written; plain first touch -> coherent
    for (int q2 = 255; q2 >= 0; --q2) { s_sufx[q2] = accu; accu += s_tsum[q2]; }
  }
  __syncthreads();
  // pass 2: descending crossing search; exactly one thread finds the k-th bin
  const unsigned kk = skk2;
  unsigned cum = s_sufx[t];
  int fbin = -1;
#pragma unroll 8
  for (int bq = 31; bq >= 0; --bq) {
    const uint4 vq = hp[t * 32 + bq];
    const unsigned hq[4] = {vq.x, vq.y, vq.z, vq.w};
#pragma unroll
    for (int u = 3; u >= 0; --u) {
      if (cum < kk && cum + hq[u] >= kk) fbin = t * 128 + bq * 4 + u;
      cum += hq[u];
    }
  }
  if (fbin >= 0) c->thrF = key_to_float(klo + (unsigned)fbin);  // plain store; boundary flushes
}

// ------- fused mask + loss: 512 blocks x 4 rows, one wave per row, NO contended atomics -------
// Per-block partials via agent-scope write-through stores; t0 waits vmcnt(0) (no L2 flush),
// then ticket; last block (singles==511) reduces with plain first-touch loads, writes out[0].
__global__ __launch_bounds__(256) void final_k(const float* __restrict__ adc,
                                               const int* __restrict__ labels,
                                               Ctl* c,
                                               float* __restrict__ out,
                                               double* __restrict__ lsum_g,
                                               unsigned* __restrict__ scnt_g) {
  __shared__ int slab[Bn];
  __shared__ double lsum[4];
  __shared__ unsigned sflag[4];
  __shared__ unsigned amlast;
  const int t = threadIdx.x;
  const int lane = t & 63, w = t >> 6;
#pragma unroll
  for (int e = 0; e < 2; ++e)                      // int4 slab staging, once per 4 rows
    ((int4*)slab)[t + 256 * e] = ((const int4*)labels)[t + 256 * e];
  __syncthreads();
  const float thr = c->thrF;
  float* __restrict__ ohnm = out + 1;
  float* __restrict__ ofin = out + 1 + (size_t)Bn * Bn;

  const int i = blockIdx.x * 4 + w;                // wave w owns one row
  const int li = slab[i];
  const float rm = adc[(size_t)i * Bn + i];        // diag == row max (bitwise)
  const float4* rowp = (const float4*)(adc + (size_t)i * Bn);
  float se = 0.0f, sp = 0.0f;
  int pc = 0;
#pragma unroll
  for (int q = 0; q < 8; ++q) {
    const int j4 = lane + 64 * q;                  // wave instr covers 1KB contiguous
    const float4 vv = rowp[j4];
    const int jb = j4 * 4;
    const float vs[4] = {vv.x, vv.y, vv.z, vv.w};
    float qh[4], qf[4];
#pragma unroll
    for (int u = 0; u < 4; ++u) {
      const int j = jb + u;
      const float L = vs[u] - rm;                  // identical fp32 value as gemm epilogue
      const bool offd = (j != i);
      const bool same = (slab[j] == li);
      const bool hnm  = offd && !same && (L >= thr);
      const bool fin  = offd && (same || hnm);
      if (offd) se += __expf(L);
      if (fin)  { sp += L; ++pc; }
      qh[u] = hnm ? 1.0f : 0.0f;
      qf[u] = fin ? 1.0f : 0.0f;
    }
    float4 h4 = {qh[0], qh[1], qh[2], qh[3]};
    float4 f4 = {qf[0], qf[1], qf[2], qf[3]};
    store16_a4(&ohnm[(size_t)i * Bn + jb], h4);    // 4-mod-16 address: memcpy path
    store16_a4(&ofin[(size_t)i * Bn + jb], f4);
  }
  float pcf = (float)pc;
#pragma unroll
  for (int o = 32; o > 0; o >>= 1) {               // wave-only reduction, no barriers
    se  += __shfl_down(se,  o, 64);
    sp  += __shfl_down(sp,  o, 64);
    pcf += __shfl_down(pcf, o, 64);
  }
  if (lane == 0) {
    const double P = (double)pcf;
    const bool single = (P == 0.0);
    const double mlpp = ((double)sp - P * log((double)se + 1e-12)) / (P + (single ? 1.0 : 0.0));
    lsum[w]  = single ? 0.0 : -mlpp;
    sflag[w] = single ? 1u : 0u;
  }
  __syncthreads();
  if (t == 0) {
    agent_store_f64(&lsum_g[blockIdx.x], lsum[0] + lsum[1] + lsum[2] + lsum[3]);
    agent_store_u32(&scnt_g[blockIdx.x], sflag[0] + sflag[1] + sflag[2] + sflag[3]);
    asm volatile("s_waitcnt vmcnt(0)" ::: "memory");  // drain sc-stores; NO L2 flush
    amlast = (atomicAdd(&c->singles, 1u) == 511u) ? 1u : 0u;
  }
  __syncthreads();
  if (!amlast) return;

  // ---- finalize tail: reduce 512 partials (plain first-touch loads; writers were sc-stores) ----
  double ls = lsum_g[t] + lsum_g[t + 256];
  unsigned sc = scnt_g[t] + scnt_g[t + 256];
#pragma unroll
  for (int o = 32; o > 0; o >>= 1) {
    ls += __shfl_down(ls, o, 64);
    sc += __shfl_down(sc, o, 64);
  }
  if (lane == 0) { lsum[w] = ls; sflag[w] = sc; }  // reuse shared arrays
  __syncthreads();
  if (t == 0) {
    const double tot = lsum[0] + lsum[1] + lsum[2] + lsum[3];
    const unsigned sg = sflag[0] + sflag[1] + sflag[2] + sflag[3];
    out[0] = (float)(tot / ((double)Bn - (double)sg));
  }
}

// ---------------- launch: 3 dispatches ----------------
extern "C" void kernel_launch(void* const* d_in, const int* in_sizes, int n_in,
                              void* d_out, int out_size, void* d_ws, size_t ws_size,
                              hipStream_t stream) {
  const float* F      = (const float*)d_in[0];
  const int*   labels = (const int*)d_in[1];
  float* out = (float*)d_out;

  char* ws = (char*)d_ws;
  Ctl*      c      = (Ctl*)ws;                              // ~131 KB
  float*    rm     = (float*)(ws + 786432);                 // 768 KB offset, 8 KB
  double*   lsum_g = (double*)(ws + 802816);                // 512 doubles, 4 KB
  unsigned* scnt_g = (unsigned*)(ws + 806912);              // 512 uints, 2 KB
  float*    adc    = (float*)(ws + (1u << 20));             // 1 MiB offset, 16.78 MB

  rowdot_k<<<32, 64, 0, stream>>>(F, rm, c);                // self-dots + Ctl zeroing
  gemm_adc<<<528, 256, 0, stream>>>(F, rm, labels, adc, c); // triangle tiles + select tail
  final_k<<<512, 256, 0, stream>>>(adc, labels, c, out, lsum_g, scnt_g); // masks+loss+finalize
}

// Round 5
// 154.172 us; speedup vs baseline: 1.2715x; 1.0093x over previous
//
#include <hip/hip_runtime.h>
#include <cstddef>

// Problem constants (match reference)
constexpr int Bn   = 2048;
constexpr int Dn   = 512;
constexpr int NCLS = 100;
constexpr unsigned WWIN = 32768;  // window width in key units (ulp = 2^-20 at |L|~14.3)
constexpr int NH = 32768;         // 1-ulp histogram bins across the window (R17)

// VERIFIED INVARIANT (R4): reference adc[i][j] = fl32( single fma chain k=0..511 ) / 0.07f,
// strict ascending k, one fused fma per step, single fp32 accumulator. DO NOT reassociate,
// split K, or use MFMA — masks flip at sub-ulp rank gaps.
// adc bitwise symmetric -> lower triangle + mirror. Row max == diag == fl32(chain(F[i]·F[i]))/0.07f.
// STABILITY (R9-R11 bisect): 528-block/256-thread gemm structure is HW-proven; single-wave
// 2080-block variant killed containers twice. Do not revisit.
// R14 LESSON (measured): gemm body is LDS-PIPE-bound: LDS:VALU ratio = 6(m+n)/mn per microtile;
// 4x4 => 3.0x (VALUBusy ~30% over ~63us body). Body floor ~58us at fixed FMA-chain semantics.
// R16 LESSON (measured): agent-scope scalar loads serialize (~700cyc each, per-load vmcnt(0));
// never bulk-scan with them. Plain first-touch loads after ticket are coherent for lines
// written only by device-scope atomics (R17-proven) or cross-kernel (R15-proven).
// R17 LESSON (measured): 1-ulp hist killed the cand scan (tail 42->12us); remaining tail cost
// is t0-SERIAL LDS-latency loops (256-iter suffix ~ LDS-latency each). R18: Hillis-Steele
// suffix scan + tree-reduce cnt^2 (all 256 threads), tail -> ~2us. Exclusive-suffix semantics
// preserved exactly -> bitwise-identical thrF. final_k back to 256 blocks x 8 rows (R0/R1
// A-B measured best).
// Mask planes start at out+1 (4-mod-16 addresses): 16B stores only via __builtin_memcpy;
// never cast to float4*.

struct Ctl {
  unsigned above;      // 0:  # negatives with key >= window hi (device atomics only)
  unsigned candCount;  // 4:  unused since R17 (layout kept)
  unsigned singles;    // 8:  final_k ticket (zeroed by rowdot)
  unsigned done;       // 12: gemm ticket (zeroed by rowdot)
  float    thrF;       // 16
  unsigned pad1;       // 20
  double   lossSum;    // 24..31 (unused; layout kept)
  unsigned hist[NH];   // 32: 1-ulp bins over window (device atomics only)
};
static_assert(offsetof(Ctl, hist) == 32, "zero loop covers head + hist");

// Monotone fp32 <-> uint32 order keys
__device__ inline unsigned key_of(float L) {
  unsigned u = __float_as_uint(L);
  return (u & 0x80000000u) ? ~u : (u | 0x80000000u);
}
__device__ inline float key_to_float(unsigned key) {
  unsigned u = (key & 0x80000000u) ? (key ^ 0x80000000u) : ~key;
  return __uint_as_float(u);
}
// Window: centered at -1/0.07 (negative-pair median), +-16384 ulps (~28 sigma of median est.)
__device__ inline unsigned wlo_key() {
  const float c0 = -1.0f / 0.07f;
  return key_of(c0) - (WWIN / 2);
}
// 16B store to a 4B-aligned address (compiler emits legal dword stores)
__device__ inline void store16_a4(float* p, float4 v) {
  __builtin_memcpy((void*)p, &v, 16);
}
// Agent-scope write-through stores (to coherent point; reader uses plain first-touch loads)
__device__ inline void agent_store_f64(double* p, double v) {
  __hip_atomic_store(p, v, __ATOMIC_RELAXED, __HIP_MEMORY_SCOPE_AGENT);
}
__device__ inline void agent_store_u32(unsigned* p, unsigned v) {
  __hip_atomic_store(p, v, __ATOMIC_RELAXED, __HIP_MEMORY_SCOPE_AGENT);
}

// ------- per-row self-dot: rm[i] bitwise == adc[i][i]; fused Ctl zeroing. 32 blocks x 64 -------
__global__ __launch_bounds__(64) void rowdot_k(const float* __restrict__ F,
                                               float* __restrict__ rm, Ctl* c) {
  const int i = blockIdx.x * 64 + threadIdx.x;
  const float4* p = (const float4*)(F + (size_t)i * Dn);
  float acc = 0.0f;
#pragma unroll 16
  for (int q = 0; q < 128; ++q) {
    const float4 f = p[q];
    acc = __builtin_fmaf(f.x, f.x, acc);
    acc = __builtin_fmaf(f.y, f.y, acc);
    acc = __builtin_fmaf(f.z, f.z, acc);
    acc = __builtin_fmaf(f.w, f.w, acc);   // strict ascending-k chain, same as gemm
  }
  rm[i] = acc / 0.07f;                     // IEEE fp32 div: bitwise == adc[i][i]
  // fused Ctl head+hist zeroing; 8 + NH = 32776 dwords (covers tickets at offs 8,12)
  unsigned* cz = (unsigned*)c;
  for (int idx = i; idx < 8 + NH; idx += 2048) cz[idx] = 0;
}

// -------- GEMM: lower-triangle 64x64 tiles + mirror + fused 1-ulp window hist --------
// + last-block (ticket==527) select tail, now fully parallel: tree-reduce cnt^2 -> k,
// Hillis-Steele suffix scan over per-thread bin sums, descending crossing search -> thrF.
// Exclusive-suffix semantics identical to R17's serial loop (bitwise-identical thrF).
__global__ __launch_bounds__(256) void gemm_adc(const float* __restrict__ F,
                                                const float* __restrict__ rm,
                                                const int* __restrict__ labels,
                                                float* __restrict__ adc, Ctl* c) {
  __shared__ float smem[4352];   // As dbuf [0,2176), Bs dbuf [2176,4352); reused: transpose, tail
  __shared__ int slabi[64], slabj[64];
  __shared__ float rmiA[64], rmjA[64];
  __shared__ unsigned abcnt;
  __shared__ unsigned amlast;
  const int t = threadIdx.x;
  int r = 0;
  { const int idx = blockIdx.x; while ((r + 1) * (r + 2) / 2 <= idx) ++r; }
  const int cc = blockIdx.x - r * (r + 1) / 2;
  const int i0 = r * 64, j0 = cc * 64;

  const int tx = t & 15, ty = t >> 4;        // 16x16 thread grid, 4x4 microtile
  const int lrow = t >> 2, lq = t & 3;       // loader: row 0..63, k-quad 0..3

  if (t < 64) {
    slabi[t] = labels[i0 + t]; rmiA[t] = rm[i0 + t];
    slabj[t] = labels[j0 + t]; rmjA[t] = rm[j0 + t];
  }
  if (t == 0) abcnt = 0;

  float acc[4][4] = {};
  const float* Ab = F + (size_t)(i0 + lrow) * Dn;
  const float* Bb = F + (size_t)(j0 + lrow) * Dn;
  float* As = smem;          // [buf*1088 + k*68 + row]
  float* Bs = smem + 2176;

  float4 a = *(const float4*)(Ab + lq * 4);
  float4 b = *(const float4*)(Bb + lq * 4);
  {
    const int k0 = lq * 4;
    As[(k0 + 0) * 68 + lrow] = a.x; As[(k0 + 1) * 68 + lrow] = a.y;
    As[(k0 + 2) * 68 + lrow] = a.z; As[(k0 + 3) * 68 + lrow] = a.w;
    Bs[(k0 + 0) * 68 + lrow] = b.x; Bs[(k0 + 1) * 68 + lrow] = b.y;
    Bs[(k0 + 2) * 68 + lrow] = b.z; Bs[(k0 + 3) * 68 + lrow] = b.w;
  }
  __syncthreads();

  for (int ch = 0; ch < 32; ++ch) {
    const int cur = ch & 1, nxt = cur ^ 1;
    if (ch < 31) {
      const int kg = (ch + 1) * 16;
      a = *(const float4*)(Ab + kg + lq * 4);
      b = *(const float4*)(Bb + kg + lq * 4);
    }
    const float* Ac = As + cur * 1088;
    const float* Bc = Bs + cur * 1088;
#pragma unroll
    for (int k = 0; k < 16; ++k) {
      const float4 av = *(const float4*)(Ac + k * 68 + ty * 4);
      const float4 bv = *(const float4*)(Bc + k * 68 + tx * 4);
      const float aa[4] = {av.x, av.y, av.z, av.w};
      const float bb[4] = {bv.x, bv.y, bv.z, bv.w};
#pragma unroll
      for (int m = 0; m < 4; ++m)
#pragma unroll
        for (int n = 0; n < 4; ++n)
          acc[m][n] = __builtin_fmaf(aa[m], bb[n], acc[m][n]);  // strict k-order chain
    }
    if (ch < 31) {
      const int k0 = lq * 4;
      float* An = As + nxt * 1088;
      float* Bm = Bs + nxt * 1088;
      An[(k0 + 0) * 68 + lrow] = a.x; An[(k0 + 1) * 68 + lrow] = a.y;
      An[(k0 + 2) * 68 + lrow] = a.z; An[(k0 + 3) * 68 + lrow] = a.w;
      Bm[(k0 + 0) * 68 + lrow] = b.x; Bm[(k0 + 1) * 68 + lrow] = b.y;
      Bm[(k0 + 2) * 68 + lrow] = b.z; Bm[(k0 + 3) * 68 + lrow] = b.w;
    }
    __syncthreads();
  }

  // epilogue: /0.07f, store own tile
  float v[4][4];
#pragma unroll
  for (int m = 0; m < 4; ++m) {
#pragma unroll
    for (int n = 0; n < 4; ++n) v[m][n] = acc[m][n] / 0.07f;   // IEEE fp32 div
    float4 q = {v[m][0], v[m][1], v[m][2], v[m][3]};
    *(float4*)&adc[(size_t)(i0 + ty * 4 + m) * Bn + j0 + tx * 4] = q;
  }
  if (r != cc) {
    // mirror via LDS transpose (bitwise-identical values)
    __syncthreads();               // block-uniform; k-loop LDS reads done
    float* T = smem;               // 64 x 68
#pragma unroll
    for (int m = 0; m < 4; ++m)
#pragma unroll
      for (int n = 0; n < 4; ++n)
        T[(tx * 4 + n) * 68 + (ty * 4 + m)] = v[m][n];
    __syncthreads();
#pragma unroll
    for (int e = 0; e < 4; ++e) {
      const int row2 = e * 16 + ty;  // mirror row = original col
      *(float4*)&adc[(size_t)(j0 + row2) * Bn + i0 + tx * 4] =
          *(const float4*)(T + row2 * 68 + tx * 4);
    }
  }

  // fused 1-ulp window histogram (own tile + mirror), values still in registers
  __syncthreads();
  const unsigned klo = wlo_key(), khi = klo + WWIN;
  unsigned myab = 0;
#pragma unroll
  for (int m = 0; m < 4; ++m) {
    const int gi = i0 + ty * 4 + m;
    const int li = slabi[ty * 4 + m];
    const float rmi = rmiA[ty * 4 + m];
#pragma unroll
    for (int n = 0; n < 4; ++n) {
      const int gj = j0 + tx * 4 + n;
      if (gi == gj || li == slabj[tx * 4 + n]) continue;
      const unsigned key = key_of(v[m][n] - rmi);   // exact fp32 sub
      if (key >= khi) ++myab;
      else if (key >= klo) atomicAdd(&c->hist[key - klo], 1u);
      if (r != cc) {
        const unsigned key2 = key_of(v[m][n] - rmjA[tx * 4 + n]);
        if (key2 >= khi) ++myab;
        else if (key2 >= klo) atomicAdd(&c->hist[key2 - klo], 1u);
      }
    }
  }
  if (myab) atomicAdd(&abcnt, myab);
  __syncthreads();
  if (t == 0 && abcnt) atomicAdd(&c->above, abcnt);

  // ---------------- last-block select tail (ticket == 527) ----------------
  __syncthreads();                 // barrier waitcnt drains this block's hist/above atomics
  if (t == 0) amlast = (atomicAdd(&c->done, 1u) == 527u) ? 1u : 0u;
  __syncthreads();
  if (!amlast) return;

  // LDS overlay (k-loop/transpose storage is dead here)
  unsigned* s_cnt  = (unsigned*)smem;          // [0,128)
  unsigned* s_tsum = (unsigned*)smem + 128;    // [128,384)
  unsigned* s_scan = (unsigned*)smem + 384;    // [384,640)
  if (t < 128) s_cnt[t] = 0;
  __syncthreads();
  for (int j = t; j < Bn; j += 256) atomicAdd(&s_cnt[labels[j]], 1u);
  __syncthreads();
  // parallel sum of cnt^2: tree-reduce over 256 slots (t >= NCLS contribute 0)
  s_scan[t] = (t < NCLS) ? s_cnt[t] * s_cnt[t] : 0u;
  __syncthreads();
#pragma unroll
  for (int off = 128; off > 0; off >>= 1) {
    if (t < off) s_scan[t] += s_scan[t + off];
    __syncthreads();
  }
  unsigned kk = (((unsigned)Bn * Bn) - s_scan[0]) >> 1;   // floor(0.5*n_neg), exact vs ref
  if (kk < 1u) kk = 1u;
  __syncthreads();                 // s_scan reuse below

  // pass 1: per-thread bin sums (plain vector loads; first touch -> coherent point)
  const uint4* hp = (const uint4*)c->hist;   // 8192 quads; thread t owns quads [t*32, t*32+32)
  unsigned s = 0;
#pragma unroll 8
  for (int bq = 0; bq < 32; ++bq) {
    const uint4 vq = hp[t * 32 + bq];
    s += vq.x + vq.y + vq.z + vq.w;
  }
  s_tsum[t] = s;
  s_scan[t] = s;
  __syncthreads();
  // Hillis-Steele inclusive SUFFIX scan: s_scan[t] = sum_{q>=t} tsum[q]
#pragma unroll
  for (int off = 1; off < 256; off <<= 1) {
    const unsigned add = (t + off < 256) ? s_scan[t + off] : 0u;
    __syncthreads();
    s_scan[t] += add;
    __syncthreads();
  }
  // exclusive suffix + above (identical semantics to R17's serial loop)
  const unsigned above = c->above;             // atomic-written; plain first touch coherent
  unsigned cum = above + s_scan[t] - s_tsum[t];
  // pass 2: descending crossing search (L2-warm reload); exactly one thread finds the bin
  int fbin = -1;
#pragma unroll 8
  for (int bq = 31; bq >= 0; --bq) {
    const uint4 vq = hp[t * 32 + bq];
    const unsigned hq[4] = {vq.x, vq.y, vq.z, vq.w};
#pragma unroll
    for (int u = 3; u >= 0; --u) {
      if (cum < kk && cum + hq[u] >= kk) fbin = t * 128 + bq * 4 + u;
      cum += hq[u];
    }
  }
  if (fbin >= 0) c->thrF = key_to_float(klo + (unsigned)fbin);  // plain store; boundary flushes
}

// ------- fused mask + loss: 256 blocks x 8 rows (R0-measured best), one wave per row -------
// Per-block partials via agent-scope write-through stores; t0 waits vmcnt(0) (no L2 flush),
// then ticket; last block (singles==255) reduces with plain first-touch loads, writes out[0].
__global__ __launch_bounds__(256) void final_k(const float* __restrict__ adc,
                                               const int* __restrict__ labels,
                                               Ctl* c,
                                               float* __restrict__ out,
                                               double* __restrict__ lsum_g,
                                               unsigned* __restrict__ scnt_g) {
  __shared__ int slab[Bn];
  __shared__ double lsum[8];
  __shared__ unsigned sflag[8];
  __shared__ unsigned amlast;
  const int t = threadIdx.x;
  const int lane = t & 63, w = t >> 6;
#pragma unroll
  for (int e = 0; e < 2; ++e)                      // int4 slab staging, once per 8 rows
    ((int4*)slab)[t + 256 * e] = ((const int4*)labels)[t + 256 * e];
  __syncthreads();
  const float thr = c->thrF;
  float* __restrict__ ohnm = out + 1;
  float* __restrict__ ofin = out + 1 + (size_t)Bn * Bn;

#pragma unroll
  for (int rr = 0; rr < 2; ++rr) {                 // wave w owns rows b*8 + rr*4 + w
    const int i = blockIdx.x * 8 + rr * 4 + w;
    const int li = slab[i];
    const float rm = adc[(size_t)i * Bn + i];      // diag == row max (bitwise)
    const float4* rowp = (const float4*)(adc + (size_t)i * Bn);
    float se = 0.0f, sp = 0.0f;
    int pc = 0;
#pragma unroll
    for (int q = 0; q < 8; ++q) {
      const int j4 = lane + 64 * q;                // wave instr covers 1KB contiguous
      const float4 vv = rowp[j4];
      const int jb = j4 * 4;
      const float vs[4] = {vv.x, vv.y, vv.z, vv.w};
      float qh[4], qf[4];
#pragma unroll
      for (int u = 0; u < 4; ++u) {
        const int j = jb + u;
        const float L = vs[u] - rm;                // identical fp32 value as gemm epilogue
        const bool offd = (j != i);
        const bool same = (slab[j] == li);
        const bool hnm  = offd && !same && (L >= thr);
        const bool fin  = offd && (same || hnm);
        if (offd) se += __expf(L);
        if (fin)  { sp += L; ++pc; }
        qh[u] = hnm ? 1.0f : 0.0f;
        qf[u] = fin ? 1.0f : 0.0f;
      }
      float4 h4 = {qh[0], qh[1], qh[2], qh[3]};
      float4 f4 = {qf[0], qf[1], qf[2], qf[3]};
      store16_a4(&ohnm[(size_t)i * Bn + jb], h4);  // 4-mod-16 address: memcpy path
      store16_a4(&ofin[(size_t)i * Bn + jb], f4);
    }
    float pcf = (float)pc;
#pragma unroll
    for (int o = 32; o > 0; o >>= 1) {             // wave-only reduction, no barriers
      se  += __shfl_down(se,  o, 64);
      sp  += __shfl_down(sp,  o, 64);
      pcf += __shfl_down(pcf, o, 64);
    }
    if (lane == 0) {
      const double P = (double)pcf;
      const bool single = (P == 0.0);
      const double mlpp = ((double)sp - P * log((double)se + 1e-12)) / (P + (single ? 1.0 : 0.0));
      lsum[w * 2 + rr]  = single ? 0.0 : -mlpp;
      sflag[w * 2 + rr] = single ? 1u : 0u;
    }
  }
  __syncthreads();
  if (t == 0) {
    double ls = 0.0;
    unsigned sc = 0;
#pragma unroll
    for (int e = 0; e < 8; ++e) { ls += lsum[e]; sc += sflag[e]; }
    agent_store_f64(&lsum_g[blockIdx.x], ls);
    agent_store_u32(&scnt_g[blockIdx.x], sc);
    asm volatile("s_waitcnt vmcnt(0)" ::: "memory");  // drain sc-stores; NO L2 flush
    amlast = (atomicAdd(&c->singles, 1u) == 255u) ? 1u : 0u;
  }
  __syncthreads();
  if (!amlast) return;

  // ---- finalize tail: reduce 256 partials (plain first-touch loads; writers were sc-stores) ----
  double ls = lsum_g[t];
  unsigned sc = scnt_g[t];
#pragma unroll
  for (int o = 32; o > 0; o >>= 1) {
    ls += __shfl_down(ls, o, 64);
    sc += __shfl_down(sc, o, 64);
  }
  if (lane == 0) { lsum[w] = ls; sflag[w] = sc; }  // reuse shared arrays (slots 0..3)
  __syncthreads();
  if (t == 0) {
    const double tot = lsum[0] + lsum[1] + lsum[2] + lsum[3];
    const unsigned sg = sflag[0] + sflag[1] + sflag[2] + sflag[3];
    out[0] = (float)(tot / ((double)Bn - (double)sg));
  }
}

// ---------------- launch: 3 dispatches ----------------
extern "C" void kernel_launch(void* const* d_in, const int* in_sizes, int n_in,
                              void* d_out, int out_size, void* d_ws, size_t ws_size,
                              hipStream_t stream) {
  const float* F      = (const float*)d_in[0];
  const int*   labels = (const int*)d_in[1];
  float* out = (float*)d_out;

  char* ws = (char*)d_ws;
  Ctl*      c      = (Ctl*)ws;                              // ~131 KB
  float*    rm     = (float*)(ws + 786432);                 // 768 KB offset, 8 KB
  double*   lsum_g = (double*)(ws + 802816);                // 512 doubles, 4 KB
  unsigned* scnt_g = (unsigned*)(ws + 806912);              // 512 uints, 2 KB
  float*    adc    = (float*)(ws + (1u << 20));             // 1 MiB offset, 16.78 MB

  rowdot_k<<<32, 64, 0, stream>>>(F, rm, c);                // self-dots + Ctl zeroing
  gemm_adc<<<528, 256, 0, stream>>>(F, rm, labels, adc, c); // triangle tiles + select tail
  final_k<<<256, 256, 0, stream>>>(adc, labels, c, out, lsum_g, scnt_g); // masks+loss+finalize
}

// Round 6
// 149.127 us; speedup vs baseline: 1.3145x; 1.0338x over previous
//
#include <hip/hip_runtime.h>
#include <cstddef>

// Problem constants (match reference)
constexpr int Bn   = 2048;
constexpr int Dn   = 512;
constexpr int NCLS = 100;
constexpr unsigned WWIN = 32768;  // window width in key units (ulp = 2^-20 at |L|~14.3)
constexpr int NH = 32768;         // 1-ulp histogram bins across the window (R17)

// VERIFIED INVARIANT (R4): reference adc[i][j] = fl32( single fma chain k=0..511 ) / 0.07f,
// strict ascending k, one fused fma per step, single fp32 accumulator. DO NOT reassociate,
// split K, or use MFMA — masks flip at sub-ulp rank gaps.
// adc bitwise symmetric -> lower triangle + mirror. Row max == diag == fl32(chain(F[i]·F[i]))/0.07f.
// STABILITY (R9-R11 bisect): 528-block/256-thread gemm structure is HW-proven; single-wave
// 2080-block variant killed containers twice. Do not revisit.
// R14 LESSON (measured): microtile LDS:VALU ratio = 6(m+n)/mn; 4x4 is the feasible optimum.
// R16 LESSON (measured): agent-scope scalar loads serialize (~700cyc each); never bulk-scan.
// R17 LESSON (measured): 1-ulp hist killed the cand-scan tail (42->12us). Plain first-touch
// loads after ticket are coherent for atomic-written lines (proven R17/R18 x2 passes).
// R18 LESSON (measured): parallelizing the tail scans bought only ~1.8us -> the ~10us tail is
// ticket serialization + lone-block latency, not the scans. gemm 74us decomposes as
// 2 shared rounds (~18 each) + straggler round (~20, 16 blocks on idle machine) + tail (~8).
// R19: BK=32 (16 chunks, half the barriers/bubbles; k order still strictly ascending ->
// bitwise-identical chains) + 8-way split tickets (528 same-address RMWs -> 66/slice).
// Mask planes start at out+1 (4-mod-16 addresses): 16B stores only via __builtin_memcpy;
// never cast to float4*.

struct Ctl {
  unsigned above;      // 0:  # negatives with key >= window hi (device atomics only)
  unsigned candCount;  // 4:  unused (layout kept)
  unsigned singles;    // 8:  final_k master ticket (zeroed by rowdot)
  unsigned done;       // 12: gemm master ticket (zeroed by rowdot)
  float    thrF;       // 16
  unsigned pad1;       // 20
  double   lossSum;    // 24..31 (unused; layout kept)
  unsigned hist[NH];   // 32: 1-ulp bins over window (device atomics only)
  unsigned done8[128]; // gemm slice tickets, stride 16 (64B apart)
  unsigned sing8[128]; // final_k slice tickets, stride 16
};
static_assert(offsetof(Ctl, hist) == 32, "zero loop covers head + hist + slices");

// Monotone fp32 <-> uint32 order keys
__device__ inline unsigned key_of(float L) {
  unsigned u = __float_as_uint(L);
  return (u & 0x80000000u) ? ~u : (u | 0x80000000u);
}
__device__ inline float key_to_float(unsigned key) {
  unsigned u = (key & 0x80000000u) ? (key ^ 0x80000000u) : ~key;
  return __uint_as_float(u);
}
// Window: centered at -1/0.07 (negative-pair median), +-16384 ulps (~28 sigma of median est.)
__device__ inline unsigned wlo_key() {
  const float c0 = -1.0f / 0.07f;
  return key_of(c0) - (WWIN / 2);
}
// 16B store to a 4B-aligned address (compiler emits legal dword stores)
__device__ inline void store16_a4(float* p, float4 v) {
  __builtin_memcpy((void*)p, &v, 16);
}
// Agent-scope write-through stores (to coherent point; reader uses plain first-touch loads)
__device__ inline void agent_store_f64(double* p, double v) {
  __hip_atomic_store(p, v, __ATOMIC_RELAXED, __HIP_MEMORY_SCOPE_AGENT);
}
__device__ inline void agent_store_u32(unsigned* p, unsigned v) {
  __hip_atomic_store(p, v, __ATOMIC_RELAXED, __HIP_MEMORY_SCOPE_AGENT);
}

// ------- per-row self-dot: rm[i] bitwise == adc[i][i]; fused Ctl zeroing. 32 blocks x 64 -------
__global__ __launch_bounds__(64) void rowdot_k(const float* __restrict__ F,
                                               float* __restrict__ rm, Ctl* c) {
  const int i = blockIdx.x * 64 + threadIdx.x;
  const float4* p = (const float4*)(F + (size_t)i * Dn);
  float acc = 0.0f;
#pragma unroll 16
  for (int q = 0; q < 128; ++q) {
    const float4 f = p[q];
    acc = __builtin_fmaf(f.x, f.x, acc);
    acc = __builtin_fmaf(f.y, f.y, acc);
    acc = __builtin_fmaf(f.z, f.z, acc);
    acc = __builtin_fmaf(f.w, f.w, acc);   // strict ascending-k chain, same as gemm
  }
  rm[i] = acc / 0.07f;                     // IEEE fp32 div: bitwise == adc[i][i]
  // fused Ctl zeroing: head(8) + hist(NH) + done8(128) + sing8(128) dwords
  unsigned* cz = (unsigned*)c;
  for (int idx = i; idx < 8 + NH + 256; idx += 2048) cz[idx] = 0;
}

// -------- GEMM: lower-triangle 64x64 tiles, BK=32 dbuf, mirror + fused 1-ulp window hist --------
// + split-ticket last-block select tail (66/slice x 8 slices -> 8 masters -> 1 tail block).
__global__ __launch_bounds__(256) void gemm_adc(const float* __restrict__ F,
                                                const float* __restrict__ rm,
                                                const int* __restrict__ labels,
                                                float* __restrict__ adc, Ctl* c) {
  __shared__ float smem[8704];   // As dbuf [0,4352), Bs dbuf [4352,8704); reused: transpose, tail
  __shared__ int slabi[64], slabj[64];
  __shared__ float rmiA[64], rmjA[64];
  __shared__ unsigned abcnt;
  __shared__ unsigned amlast;
  const int t = threadIdx.x;
  int r = 0;
  { const int idx = blockIdx.x; while ((r + 1) * (r + 2) / 2 <= idx) ++r; }
  const int cc = blockIdx.x - r * (r + 1) / 2;
  const int i0 = r * 64, j0 = cc * 64;

  const int tx = t & 15, ty = t >> 4;        // 16x16 thread grid, 4x4 microtile
  const int lrow = t >> 2, lq = t & 3;       // loader: row 0..63, k-quad 0..3 (+16 for hi half)

  if (t < 64) {
    slabi[t] = labels[i0 + t]; rmiA[t] = rm[i0 + t];
    slabj[t] = labels[j0 + t]; rmjA[t] = rm[j0 + t];
  }
  if (t == 0) abcnt = 0;

  float acc[4][4] = {};
  const float* Ab = F + (size_t)(i0 + lrow) * Dn;
  const float* Bb = F + (size_t)(j0 + lrow) * Dn;
  float* As = smem;           // [buf*2176 + k*68 + row], k 0..31
  float* Bs = smem + 4352;

  float4 a0 = *(const float4*)(Ab + lq * 4);
  float4 a1 = *(const float4*)(Ab + lq * 4 + 16);
  float4 b0 = *(const float4*)(Bb + lq * 4);
  float4 b1 = *(const float4*)(Bb + lq * 4 + 16);
  {
    const int k0 = lq * 4;
    As[(k0 + 0) * 68 + lrow] = a0.x; As[(k0 + 1) * 68 + lrow] = a0.y;
    As[(k0 + 2) * 68 + lrow] = a0.z; As[(k0 + 3) * 68 + lrow] = a0.w;
    As[(k0 + 16) * 68 + lrow] = a1.x; As[(k0 + 17) * 68 + lrow] = a1.y;
    As[(k0 + 18) * 68 + lrow] = a1.z; As[(k0 + 19) * 68 + lrow] = a1.w;
    Bs[(k0 + 0) * 68 + lrow] = b0.x; Bs[(k0 + 1) * 68 + lrow] = b0.y;
    Bs[(k0 + 2) * 68 + lrow] = b0.z; Bs[(k0 + 3) * 68 + lrow] = b0.w;
    Bs[(k0 + 16) * 68 + lrow] = b1.x; Bs[(k0 + 17) * 68 + lrow] = b1.y;
    Bs[(k0 + 18) * 68 + lrow] = b1.z; Bs[(k0 + 19) * 68 + lrow] = b1.w;
  }
  __syncthreads();

  for (int ch = 0; ch < 16; ++ch) {
    const int cur = ch & 1, nxt = cur ^ 1;
    if (ch < 15) {
      const int kg = (ch + 1) * 32;
      a0 = *(const float4*)(Ab + kg + lq * 4);
      a1 = *(const float4*)(Ab + kg + lq * 4 + 16);
      b0 = *(const float4*)(Bb + kg + lq * 4);
      b1 = *(const float4*)(Bb + kg + lq * 4 + 16);
    }
    const float* Ac = As + cur * 2176;
    const float* Bc = Bs + cur * 2176;
#pragma unroll
    for (int k = 0; k < 32; ++k) {           // global k = ch*32 + k, strictly ascending
      const float4 av = *(const float4*)(Ac + k * 68 + ty * 4);
      const float4 bv = *(const float4*)(Bc + k * 68 + tx * 4);
      const float aa[4] = {av.x, av.y, av.z, av.w};
      const float bb[4] = {bv.x, bv.y, bv.z, bv.w};
#pragma unroll
      for (int m = 0; m < 4; ++m)
#pragma unroll
        for (int n = 0; n < 4; ++n)
          acc[m][n] = __builtin_fmaf(aa[m], bb[n], acc[m][n]);  // strict k-order chain
    }
    if (ch < 15) {
      const int k0 = lq * 4;
      float* An = As + nxt * 2176;
      float* Bm = Bs + nxt * 2176;
      An[(k0 + 0) * 68 + lrow] = a0.x; An[(k0 + 1) * 68 + lrow] = a0.y;
      An[(k0 + 2) * 68 + lrow] = a0.z; An[(k0 + 3) * 68 + lrow] = a0.w;
      An[(k0 + 16) * 68 + lrow] = a1.x; An[(k0 + 17) * 68 + lrow] = a1.y;
      An[(k0 + 18) * 68 + lrow] = a1.z; An[(k0 + 19) * 68 + lrow] = a1.w;
      Bm[(k0 + 0) * 68 + lrow] = b0.x; Bm[(k0 + 1) * 68 + lrow] = b0.y;
      Bm[(k0 + 2) * 68 + lrow] = b0.z; Bm[(k0 + 3) * 68 + lrow] = b0.w;
      Bm[(k0 + 16) * 68 + lrow] = b1.x; Bm[(k0 + 17) * 68 + lrow] = b1.y;
      Bm[(k0 + 18) * 68 + lrow] = b1.z; Bm[(k0 + 19) * 68 + lrow] = b1.w;
    }
    __syncthreads();
  }

  // epilogue: /0.07f, store own tile
  float v[4][4];
#pragma unroll
  for (int m = 0; m < 4; ++m) {
#pragma unroll
    for (int n = 0; n < 4; ++n) v[m][n] = acc[m][n] / 0.07f;   // IEEE fp32 div
    float4 q = {v[m][0], v[m][1], v[m][2], v[m][3]};
    *(float4*)&adc[(size_t)(i0 + ty * 4 + m) * Bn + j0 + tx * 4] = q;
  }
  if (r != cc) {
    // mirror via LDS transpose (bitwise-identical values)
    __syncthreads();               // block-uniform; k-loop LDS reads done
    float* T = smem;               // 64 x 68
#pragma unroll
    for (int m = 0; m < 4; ++m)
#pragma unroll
      for (int n = 0; n < 4; ++n)
        T[(tx * 4 + n) * 68 + (ty * 4 + m)] = v[m][n];
    __syncthreads();
#pragma unroll
    for (int e = 0; e < 4; ++e) {
      const int row2 = e * 16 + ty;  // mirror row = original col
      *(float4*)&adc[(size_t)(j0 + row2) * Bn + i0 + tx * 4] =
          *(const float4*)(T + row2 * 68 + tx * 4);
    }
  }

  // fused 1-ulp window histogram (own tile + mirror), values still in registers
  __syncthreads();
  const unsigned klo = wlo_key(), khi = klo + WWIN;
  unsigned myab = 0;
#pragma unroll
  for (int m = 0; m < 4; ++m) {
    const int gi = i0 + ty * 4 + m;
    const int li = slabi[ty * 4 + m];
    const float rmi = rmiA[ty * 4 + m];
#pragma unroll
    for (int n = 0; n < 4; ++n) {
      const int gj = j0 + tx * 4 + n;
      if (gi == gj || li == slabj[tx * 4 + n]) continue;
      const unsigned key = key_of(v[m][n] - rmi);   // exact fp32 sub
      if (key >= khi) ++myab;
      else if (key >= klo) atomicAdd(&c->hist[key - klo], 1u);
      if (r != cc) {
        const unsigned key2 = key_of(v[m][n] - rmjA[tx * 4 + n]);
        if (key2 >= khi) ++myab;
        else if (key2 >= klo) atomicAdd(&c->hist[key2 - klo], 1u);
      }
    }
  }
  if (myab) atomicAdd(&abcnt, myab);
  __syncthreads();
  if (t == 0 && abcnt) atomicAdd(&c->above, abcnt);

  // ------------- split-ticket select tail (66/slice x 8 -> 8 masters -> 1 tail) -------------
  __syncthreads();                 // barrier waitcnt drains this block's hist/above atomics
  if (t == 0) {
    const int sl = (int)(blockIdx.x & 7);
    unsigned am = 0u;
    if (atomicAdd(&c->done8[sl * 16], 1u) == 65u)
      am = (atomicAdd(&c->done, 1u) == 7u) ? 1u : 0u;
    amlast = am;
  }
  __syncthreads();
  if (!amlast) return;

  // LDS overlay (k-loop/transpose storage is dead here)
  unsigned* s_cnt  = (unsigned*)smem;          // [0,128)
  unsigned* s_tsum = (unsigned*)smem + 128;    // [128,384)
  unsigned* s_scan = (unsigned*)smem + 384;    // [384,640)
  if (t < 128) s_cnt[t] = 0;
  __syncthreads();
  for (int j = t; j < Bn; j += 256) atomicAdd(&s_cnt[labels[j]], 1u);
  __syncthreads();
  // parallel sum of cnt^2: tree-reduce over 256 slots (t >= NCLS contribute 0)
  s_scan[t] = (t < NCLS) ? s_cnt[t] * s_cnt[t] : 0u;
  __syncthreads();
#pragma unroll
  for (int off = 128; off > 0; off >>= 1) {
    if (t < off) s_scan[t] += s_scan[t + off];
    __syncthreads();
  }
  unsigned kk = (((unsigned)Bn * Bn) - s_scan[0]) >> 1;   // floor(0.5*n_neg), exact vs ref
  if (kk < 1u) kk = 1u;
  __syncthreads();                 // s_scan reuse below

  // pass 1: per-thread bin sums (plain vector loads; first touch -> coherent point)
  const uint4* hp = (const uint4*)c->hist;   // 8192 quads; thread t owns quads [t*32, t*32+32)
  unsigned s = 0;
#pragma unroll 8
  for (int bq = 0; bq < 32; ++bq) {
    const uint4 vq = hp[t * 32 + bq];
    s += vq.x + vq.y + vq.z + vq.w;
  }
  s_tsum[t] = s;
  s_scan[t] = s;
  __syncthreads();
  // Hillis-Steele inclusive SUFFIX scan: s_scan[t] = sum_{q>=t} tsum[q]
#pragma unroll
  for (int off = 1; off < 256; off <<= 1) {
    const unsigned add = (t + off < 256) ? s_scan[t + off] : 0u;
    __syncthreads();
    s_scan[t] += add;
    __syncthreads();
  }
  // exclusive suffix + above (identical semantics to R17's serial loop)
  const unsigned above = c->above;             // atomic-written; plain first touch coherent
  unsigned cum = above + s_scan[t] - s_tsum[t];
  // pass 2: descending crossing search (L2-warm reload); exactly one thread finds the bin
  int fbin = -1;
#pragma unroll 8
  for (int bq = 31; bq >= 0; --bq) {
    const uint4 vq = hp[t * 32 + bq];
    const unsigned hq[4] = {vq.x, vq.y, vq.z, vq.w};
#pragma unroll
    for (int u = 3; u >= 0; --u) {
      if (cum < kk && cum + hq[u] >= kk) fbin = t * 128 + bq * 4 + u;
      cum += hq[u];
    }
  }
  if (fbin >= 0) c->thrF = key_to_float(klo + (unsigned)fbin);  // plain store; boundary flushes
}

// ------- fused mask + loss: 256 blocks x 8 rows, one wave per row; split-ticket finalize -------
__global__ __launch_bounds__(256) void final_k(const float* __restrict__ adc,
                                               const int* __restrict__ labels,
                                               Ctl* c,
                                               float* __restrict__ out,
                                               double* __restrict__ lsum_g,
                                               unsigned* __restrict__ scnt_g) {
  __shared__ int slab[Bn];
  __shared__ double lsum[8];
  __shared__ unsigned sflag[8];
  __shared__ unsigned amlast;
  const int t = threadIdx.x;
  const int lane = t & 63, w = t >> 6;
#pragma unroll
  for (int e = 0; e < 2; ++e)                      // int4 slab staging, once per 8 rows
    ((int4*)slab)[t + 256 * e] = ((const int4*)labels)[t + 256 * e];
  __syncthreads();
  const float thr = c->thrF;
  float* __restrict__ ohnm = out + 1;
  float* __restrict__ ofin = out + 1 + (size_t)Bn * Bn;

#pragma unroll
  for (int rr = 0; rr < 2; ++rr) {                 // wave w owns rows b*8 + rr*4 + w
    const int i = blockIdx.x * 8 + rr * 4 + w;
    const int li = slab[i];
    const float rm = adc[(size_t)i * Bn + i];      // diag == row max (bitwise)
    const float4* rowp = (const float4*)(adc + (size_t)i * Bn);
    float se = 0.0f, sp = 0.0f;
    int pc = 0;
#pragma unroll
    for (int q = 0; q < 8; ++q) {
      const int j4 = lane + 64 * q;                // wave instr covers 1KB contiguous
      const float4 vv = rowp[j4];
      const int jb = j4 * 4;
      const float vs[4] = {vv.x, vv.y, vv.z, vv.w};
      float qh[4], qf[4];
#pragma unroll
      for (int u = 0; u < 4; ++u) {
        const int j = jb + u;
        const float L = vs[u] - rm;                // identical fp32 value as gemm epilogue
        const bool offd = (j != i);
        const bool same = (slab[j] == li);
        const bool hnm  = offd && !same && (L >= thr);
        const bool fin  = offd && (same || hnm);
        if (offd) se += __expf(L);
        if (fin)  { sp += L; ++pc; }
        qh[u] = hnm ? 1.0f : 0.0f;
        qf[u] = fin ? 1.0f : 0.0f;
      }
      float4 h4 = {qh[0], qh[1], qh[2], qh[3]};
      float4 f4 = {qf[0], qf[1], qf[2], qf[3]};
      store16_a4(&ohnm[(size_t)i * Bn + jb], h4);  // 4-mod-16 address: memcpy path
      store16_a4(&ofin[(size_t)i * Bn + jb], f4);
    }
    float pcf = (float)pc;
#pragma unroll
    for (int o = 32; o > 0; o >>= 1) {             // wave-only reduction, no barriers
      se  += __shfl_down(se,  o, 64);
      sp  += __shfl_down(sp,  o, 64);
      pcf += __shfl_down(pcf, o, 64);
    }
    if (lane == 0) {
      const double P = (double)pcf;
      const bool single = (P == 0.0);
      const double mlpp = ((double)sp - P * log((double)se + 1e-12)) / (P + (single ? 1.0 : 0.0));
      lsum[w * 2 + rr]  = single ? 0.0 : -mlpp;
      sflag[w * 2 + rr] = single ? 1u : 0u;
    }
  }
  __syncthreads();
  if (t == 0) {
    double ls = 0.0;
    unsigned sc = 0;
#pragma unroll
    for (int e = 0; e < 8; ++e) { ls += lsum[e]; sc += sflag[e]; }
    agent_store_f64(&lsum_g[blockIdx.x], ls);
    agent_store_u32(&scnt_g[blockIdx.x], sc);
    asm volatile("s_waitcnt vmcnt(0)" ::: "memory");  // drain sc-stores; NO L2 flush
    const int sl = (int)(blockIdx.x & 7);
    unsigned am = 0u;
    if (atomicAdd(&c->sing8[sl * 16], 1u) == 31u)
      am = (atomicAdd(&c->singles, 1u) == 7u) ? 1u : 0u;
    amlast = am;
  }
  __syncthreads();
  if (!amlast) return;

  // ---- finalize tail: reduce 256 partials (plain first-touch loads; writers were sc-stores) ----
  double ls = lsum_g[t];
  unsigned sc = scnt_g[t];
#pragma unroll
  for (int o = 32; o > 0; o >>= 1) {
    ls += __shfl_down(ls, o, 64);
    sc += __shfl_down(sc, o, 64);
  }
  if (lane == 0) { lsum[w] = ls; sflag[w] = sc; }  // reuse shared arrays (slots 0..3)
  __syncthreads();
  if (t == 0) {
    const double tot = lsum[0] + lsum[1] + lsum[2] + lsum[3];
    const unsigned sg = sflag[0] + sflag[1] + sflag[2] + sflag[3];
    out[0] = (float)(tot / ((double)Bn - (double)sg));
  }
}

// ---------------- launch: 3 dispatches ----------------
extern "C" void kernel_launch(void* const* d_in, const int* in_sizes, int n_in,
                              void* d_out, int out_size, void* d_ws, size_t ws_size,
                              hipStream_t stream) {
  const float* F      = (const float*)d_in[0];
  const int*   labels = (const int*)d_in[1];
  float* out = (float*)d_out;

  char* ws = (char*)d_ws;
  Ctl*      c      = (Ctl*)ws;                              // ~132 KB
  float*    rm     = (float*)(ws + 786432);                 // 768 KB offset, 8 KB
  double*   lsum_g = (double*)(ws + 802816);                // 512 doubles, 4 KB
  unsigned* scnt_g = (unsigned*)(ws + 806912);              // 512 uints, 2 KB
  float*    adc    = (float*)(ws + (1u << 20));             // 1 MiB offset, 16.78 MB

  rowdot_k<<<32, 64, 0, stream>>>(F, rm, c);                // self-dots + Ctl zeroing
  gemm_adc<<<528, 256, 0, stream>>>(F, rm, labels, adc, c); // BK=32 tiles + select tail
  final_k<<<256, 256, 0, stream>>>(adc, labels, c, out, lsum_g, scnt_g); // masks+loss+finalize
}